// Round 5
// baseline (217.069 us; speedup 1.0000x reference)
//
#include <hip/hip_runtime.h>
#include <stdint.h>

// A2aSparseMLP: B=1, S=2048, H=1024, I=1024, E=8, TOP_K=2, ALPHA=1.702, LIMIT=7
// Round 5: streaming-transpose weight pre-passes (contiguous 1KB reads ->
// LDS transpose -> coalesced frag-order writes), gemm1 panel via contiguous
// 64KB global_load_lds. gemm2 unchanged from round 4. w2f aliases w1f.

#define Sd 2048
#define Hd 1024
#define Id 1024

typedef __bf16 bf16x8 __attribute__((ext_vector_type(8)));
typedef float f32x4 __attribute__((ext_vector_type(4)));

__device__ __forceinline__ f32x4 mfma_bf16(bf16x8 a, bf16x8 b, f32x4 c) {
  return __builtin_amdgcn_mfma_f32_16x16x32_bf16(a, b, c, 0, 0, 0);
}

__device__ __forceinline__ void gload16(const __bf16* g, __bf16* l) {
  __builtin_amdgcn_global_load_lds(
      (const __attribute__((address_space(1))) unsigned int*)g,
      (__attribute__((address_space(3))) unsigned int*)l, 16, 0, 0);
}

__device__ __forceinline__ unsigned int packbf(float lo, float hi) {
  __bf16 a = (__bf16)lo, b = (__bf16)hi;
  return (unsigned int)__builtin_bit_cast(unsigned short, a) |
         ((unsigned int)__builtin_bit_cast(unsigned short, b) << 16);
}

// ---------------- router ----------------
__global__ __launch_bounds__(256) void k_router(
    const float* __restrict__ x, const float* __restrict__ rw,
    const float* __restrict__ rb, float* __restrict__ scores,
    float* __restrict__ topw, int* __restrict__ cnt, int* __restrict__ assign) {
  const int lane = threadIdx.x & 63;
  const int t = blockIdx.x * 4 + (threadIdx.x >> 6);
  float acc[8];
#pragma unroll
  for (int e = 0; e < 8; ++e) acc[e] = 0.f;
  const float* xr = x + (size_t)t * Hd;
#pragma unroll
  for (int j = 0; j < 16; ++j) {
    int h = j * 64 + lane;
    float xv = xr[h];
    const float4* wp = (const float4*)(rw + h * 8);
    float4 w0 = wp[0], w1 = wp[1];
    acc[0] += xv * w0.x; acc[1] += xv * w0.y;
    acc[2] += xv * w0.z; acc[3] += xv * w0.w;
    acc[4] += xv * w1.x; acc[5] += xv * w1.y;
    acc[6] += xv * w1.z; acc[7] += xv * w1.w;
  }
#pragma unroll
  for (int m = 32; m >= 1; m >>= 1) {
#pragma unroll
    for (int e = 0; e < 8; ++e) acc[e] += __shfl_xor(acc[e], m, 64);
  }
  if (lane == 0) {
    float lg[8];
#pragma unroll
    for (int e = 0; e < 8; ++e) lg[e] = acc[e] + rb[e];
    int i0 = 0; float v0 = lg[0];
#pragma unroll
    for (int e = 1; e < 8; ++e) if (lg[e] > v0) { v0 = lg[e]; i0 = e; }
    int i1 = -1; float v1 = -3.4e38f;
#pragma unroll
    for (int e = 0; e < 8; ++e) if (e != i0 && lg[e] > v1) { v1 = lg[e]; i1 = e; }
    float e1 = __expf(v1 - v0);
    float s = 1.f + e1;
    float w0 = 1.f / s, w1v = e1 / s;
#pragma unroll
    for (int e = 0; e < 8; ++e)
      scores[t * 8 + e] = (e == i0) ? w0 : ((e == i1) ? w1v : 0.f);
    topw[t * 2] = w0;
    topw[t * 2 + 1] = w1v;
    int s0 = atomicAdd(&cnt[i0], 1); assign[i0 * 2048 + s0] = t * 2;
    int s1 = atomicAdd(&cnt[i1], 1); assign[i1 * 2048 + s1] = t * 2 + 1;
  }
}

// ---------------- x f32 -> bf16 ----------------
__global__ __launch_bounds__(256) void k_prex(const float* __restrict__ x,
                                              __bf16* __restrict__ xb) {
  int i = blockIdx.x * 256 + threadIdx.x;
  const float4* p = (const float4*)(x + (size_t)i * 8);
  float4 f0 = p[0], f1 = p[1];
  bf16x8 v;
  v[0] = (__bf16)f0.x; v[1] = (__bf16)f0.y; v[2] = (__bf16)f0.z; v[3] = (__bf16)f0.w;
  v[4] = (__bf16)f1.x; v[5] = (__bf16)f1.y; v[6] = (__bf16)f1.z; v[7] = (__bf16)f1.w;
  *(bf16x8*)(xb + (size_t)i * 8) = v;
}

// ------ pre1: wgu f32 (row-major, g/u interleaved) -> w1f bf16 frag order ------
// Streaming transpose. Tile: 64 h-rows x 256 floats (=128 real i). Grid:
// e(8) x kt(16) x nt(8). Output row = ((e*64+it)*2+vf)*32 + k32, 512 bf16.
__global__ __launch_bounds__(256) void k_pre1(const float* __restrict__ wgu,
                                              __bf16* __restrict__ w1f) {
  const int b = blockIdx.x;
  const int nt = b & 7, kt = (b >> 3) & 15, e = b >> 7;
  __shared__ unsigned int Ls[16][16][34];  // [vu][c][r], r = rowpair
  const int tid = threadIdx.x;
  const int w = tid >> 6, lane = tid & 63;
  const float* src = wgu + (size_t)e * (1024 * 2048) +
                     (size_t)(kt * 64 + w * 16) * 2048 + nt * 256;
  const int i0 = lane * 2;
  const int c0 = i0 & 15, u0 = (i0 >> 4) * 2;
  const int c1 = (i0 + 1) & 15, u1 = ((i0 + 1) >> 4) * 2;
#pragma unroll
  for (int rp = 0; rp < 8; ++rp) {
    float4 fa = *(const float4*)(src + (size_t)(rp * 2) * 2048 + lane * 4);
    float4 fb = *(const float4*)(src + (size_t)(rp * 2 + 1) * 2048 + lane * 4);
    int r = w * 8 + rp;
    Ls[u0][c0][r] = packbf(fa.x, fb.x);      // gate(i0)
    Ls[u0 + 1][c0][r] = packbf(fa.y, fb.y);  // up(i0)
    Ls[u1][c1][r] = packbf(fa.z, fb.z);      // gate(i0+1)
    Ls[u1 + 1][c1][r] = packbf(fa.w, fb.w);  // up(i0+1)
  }
  __syncthreads();
  const int khi = lane >> 4, c = lane & 15;
#pragma unroll
  for (int uu = 0; uu < 8; ++uu) {
    int ul = w * 8 + uu, vu = ul >> 1, k32l = ul & 1;
    const unsigned int* p = &Ls[vu][c][k32l * 16 + khi * 4];
    uint2 q0 = *(const uint2*)p;
    uint2 q1 = *(const uint2*)(p + 2);
    int itg = nt * 8 + (vu >> 1), vf = vu & 1;
    size_t row = ((size_t)(e * 64 + itg) * 2 + vf) * 32 + (kt * 2 + k32l);
    uint4 o = {q0.x, q0.y, q1.x, q1.y};
    *(uint4*)(w1f + row * 512 + lane * 8) = o;
  }
}

// ------ pre2: wdn f32 -> w2f bf16 frag order (streaming transpose) ------
// Tile: 64 k-rows x 256 n-cols. Grid: e(8) x kt(16) x nt(4).
// Output row = (e*64 + F)*32 + k32, F = n>>4.
__global__ __launch_bounds__(256) void k_pre2(const float* __restrict__ wdn,
                                              __bf16* __restrict__ w2f) {
  const int b = blockIdx.x;
  const int nt = b & 3, kt = (b >> 2) & 15, e = b >> 6;
  __shared__ unsigned int Ls[16][16][34];  // [F'][c][r]
  const int tid = threadIdx.x;
  const int w = tid >> 6, lane = tid & 63;
  const float* src = wdn + (size_t)e * (1024 * 1024) +
                     (size_t)(kt * 64 + w * 16) * 1024 + nt * 256;
#pragma unroll
  for (int rp = 0; rp < 8; ++rp) {
    float4 fa = *(const float4*)(src + (size_t)(rp * 2) * 1024 + lane * 4);
    float4 fb = *(const float4*)(src + (size_t)(rp * 2 + 1) * 1024 + lane * 4);
    int r = w * 8 + rp;
    float va[4] = {fa.x, fa.y, fa.z, fa.w};
    float vb[4] = {fb.x, fb.y, fb.z, fb.w};
#pragma unroll
    for (int q = 0; q < 4; ++q) {
      int cl = lane * 4 + q;
      Ls[cl >> 4][cl & 15][r] = packbf(va[q], vb[q]);
    }
  }
  __syncthreads();
  const int khi = lane >> 4, c = lane & 15;
#pragma unroll
  for (int uu = 0; uu < 8; ++uu) {
    int ul = w * 8 + uu, Fl = ul >> 1, k32l = ul & 1;
    const unsigned int* p = &Ls[Fl][c][k32l * 16 + khi * 4];
    uint2 q0 = *(const uint2*)p;
    uint2 q1 = *(const uint2*)(p + 2);
    size_t row = (size_t)(e * 64 + nt * 16 + Fl) * 32 + (kt * 2 + k32l);
    uint4 o = {q0.x, q0.y, q1.x, q1.y};
    *(uint4*)(w2f + row * 512 + lane * 8) = o;
  }
}

// ------ GEMM1: B-resident (e, it: 16 act cols), contiguous 64KB panel ------
__global__ __launch_bounds__(256, 2) void k_gemm1(
    const __bf16* __restrict__ xb, const __bf16* __restrict__ w1f,
    const float* __restrict__ gub, const int* __restrict__ cnt,
    const int* __restrict__ assign, __bf16* __restrict__ abuf) {
  const int it = blockIdx.x & 63;
  const int e = blockIdx.x >> 6;
  const int n = cnt[e];
  if (n <= 0) return;
  __shared__ __align__(16) __bf16 Bs[2][32][512];
  __shared__ __align__(16) __bf16 Ts[256][16];
  __shared__ int ent[256];
  const int tid = threadIdx.x;
  const int lane = tid & 63;
  const int wm = tid >> 6;

  // stage B panel once: contiguous 64 KB via global_load_lds
  const __bf16* wbase = w1f + (size_t)((e * 64 + it) * 2) * (32 * 512);
  __bf16* bsf = &Bs[0][0][0];
#pragma unroll
  for (int s = 0; s < 16; ++s) {
    int idx = s * 256 + tid;
    gload16(wbase + (size_t)idx * 8, bsf + (size_t)idx * 8);
  }
  const int iCol = it * 16 + (lane & 15);
  const float bg = gub[e * 2048 + 2 * iCol];
  const float bu = gub[e * 2048 + 2 * iCol + 1];
  int eb = 0;
#pragma unroll
  for (int q = 0; q < 8; ++q) eb += (q < e) ? (((cnt[q] + 255) >> 8) << 8) : 0;
  const int u0 = eb >> 4;
  const int nmt = (n + 255) >> 8;

  for (int mt = 0; mt < nmt; ++mt) {
    {
      int slot = mt * 256 + tid;
      ent[tid] = (slot < n) ? assign[e * 2048 + slot] : -1;
    }
    __syncthreads();  // publish ent; first iter also drains panel gloads
    const __bf16* ap[4];
#pragma unroll
    for (int mi = 0; mi < 4; ++mi) {
      int en = ent[wm * 64 + mi * 16 + (lane & 15)];
      int tok = (en >= 0) ? (en >> 1) : 0;
      ap[mi] = xb + (size_t)tok * Hd + ((lane >> 4) * 8);
    }
    bf16x8 apf[4];
#pragma unroll
    for (int mi = 0; mi < 4; ++mi) apf[mi] = *(const bf16x8*)(ap[mi]);
    f32x4 acc[4][2];
#pragma unroll
    for (int a = 0; a < 4; ++a)
#pragma unroll
      for (int b = 0; b < 2; ++b) acc[a][b] = (f32x4){0.f, 0.f, 0.f, 0.f};

#pragma unroll 4
    for (int ks = 0; ks < 32; ++ks) {
      bf16x8 acur[4];
#pragma unroll
      for (int mi = 0; mi < 4; ++mi) acur[mi] = apf[mi];
      if (ks < 31) {
#pragma unroll
        for (int mi = 0; mi < 4; ++mi)
          apf[mi] = *(const bf16x8*)(ap[mi] + (ks + 1) * 32);
      }
      bf16x8 b[2];
#pragma unroll
      for (int ni = 0; ni < 2; ++ni)
        b[ni] = *(const bf16x8*)&Bs[ni][ks][lane * 8];
#pragma unroll
      for (int mi = 0; mi < 4; ++mi)
#pragma unroll
        for (int ni = 0; ni < 2; ++ni)
          acc[mi][ni] = mfma_bf16(acur[mi], b[ni], acc[mi][ni]);
    }
    // epilogue: GLU -> Ts
#pragma unroll
    for (int mi = 0; mi < 4; ++mi) {
#pragma unroll
      for (int rr = 0; rr < 4; ++rr) {
        int row = wm * 64 + mi * 16 + (lane >> 4) * 4 + rr;
        float g = fminf(acc[mi][0][rr] + bg, 7.f);
        float u = fminf(fmaxf(acc[mi][1][rr] + bu, -7.f), 7.f);
        float sg = 1.f / (1.f + __expf(-1.702f * g));
        Ts[row][lane & 15] = (__bf16)((u + 1.f) * (g * sg));
      }
    }
    __syncthreads();  // Ts ready
#pragma unroll
    for (int it2 = 0; it2 < 2; ++it2) {
      int idx = it2 * 256 + tid;
      int r = idx & 15, hl = (idx >> 4) & 1, sbl = idx >> 5;
      bf16x8 v = *(const bf16x8*)&Ts[sbl * 16 + r][hl * 8];
      size_t o = (((size_t)(u0 + mt * 16 + sbl) * 32) + (it >> 1)) * 512 +
                 ((((it & 1) * 2 + hl) * 16 + r) * 8);
      *(bf16x8*)(abuf + o) = v;
    }
    __syncthreads();  // Ts reads done before next iter's writes
  }
}

// ------ GEMM2: B-resident (e, ht: 32 h cols, ms), loops over mtiles ------
__global__ __launch_bounds__(256, 2) void k_gemm2(
    const __bf16* __restrict__ abuf, const __bf16* __restrict__ w2f,
    const float* __restrict__ dnb, const int* __restrict__ cnt,
    const int* __restrict__ assign, const float* __restrict__ topw,
    float* __restrict__ out) {
  const int ms = blockIdx.x & 1;
  const int ht = (blockIdx.x >> 1) & 31;
  const int e = blockIdx.x >> 6;
  const int n = cnt[e];
  if (n <= 0) return;
  __shared__ __align__(16) __bf16 Bs[2][32][512];
  __shared__ int ent[256];
  __shared__ float wgt[256];
  const int tid = threadIdx.x;
  const int lane = tid & 63;
  const int wm = tid >> 6;

  const __bf16* wbase = w2f + (size_t)(e * 64 + ht * 2) * (32 * 512);
  __bf16* bsf = &Bs[0][0][0];
#pragma unroll
  for (int s = 0; s < 16; ++s) {
    int idx = s * 256 + tid;
    gload16(wbase + (size_t)idx * 8, bsf + (size_t)idx * 8);
  }
  int eb = 0;
#pragma unroll
  for (int q = 0; q < 8; ++q) eb += (q < e) ? (((cnt[q] + 255) >> 8) << 8) : 0;
  const int u0 = eb >> 4;
  const int nmt = (n + 255) >> 8;

  for (int mt = ms; mt < nmt; mt += 2) {
    __syncthreads();  // prev epilogue's ent/wgt reads done
    {
      int slot = mt * 256 + tid;
      int en = (slot < n) ? assign[e * 2048 + slot] : -1;
      ent[tid] = en;
      wgt[tid] = (en >= 0) ? topw[en] : 0.f;
    }
    __syncthreads();  // publish (also drains panel gloads on first iter)
    const __bf16* ab = abuf + ((size_t)(u0 + mt * 16 + wm * 4) * 32) * 512 +
                       lane * 8;
    bf16x8 apf[4];
#pragma unroll
    for (int mi = 0; mi < 4; ++mi)
      apf[mi] = *(const bf16x8*)(ab + (size_t)mi * 32 * 512);
    f32x4 acc[4][2];
#pragma unroll
    for (int a = 0; a < 4; ++a)
#pragma unroll
      for (int b = 0; b < 2; ++b) acc[a][b] = (f32x4){0.f, 0.f, 0.f, 0.f};

#pragma unroll 4
    for (int ks = 0; ks < 32; ++ks) {
      bf16x8 acur[4];
#pragma unroll
      for (int mi = 0; mi < 4; ++mi) acur[mi] = apf[mi];
      if (ks < 31) {
#pragma unroll
        for (int mi = 0; mi < 4; ++mi)
          apf[mi] = *(const bf16x8*)(ab + (size_t)mi * 32 * 512 + (ks + 1) * 512);
      }
      bf16x8 b[2];
#pragma unroll
      for (int ni = 0; ni < 2; ++ni)
        b[ni] = *(const bf16x8*)&Bs[ni][ks][lane * 8];
#pragma unroll
      for (int mi = 0; mi < 4; ++mi)
#pragma unroll
        for (int ni = 0; ni < 2; ++ni)
          acc[mi][ni] = mfma_bf16(acur[mi], b[ni], acc[mi][ni]);
    }
#pragma unroll
    for (int ni = 0; ni < 2; ++ni) {
      const int nn = ht * 32 + ni * 16 + (lane & 15);
      const float bias = dnb[e * 1024 + nn];
#pragma unroll
      for (int mi = 0; mi < 4; ++mi) {
#pragma unroll
        for (int rr = 0; rr < 4; ++rr) {
          int row = wm * 64 + mi * 16 + (lane >> 4) * 4 + rr;
          int en = ent[row];
          if (en >= 0)
            atomicAdd(out + (size_t)(en >> 1) * Hd + nn,
                      wgt[row] * (acc[mi][ni][rr] + bias));
        }
      }
    }
  }
}

extern "C" void kernel_launch(void* const* d_in, const int* in_sizes, int n_in,
                              void* d_out, int out_size, void* d_ws, size_t ws_size,
                              hipStream_t stream) {
  const float* x   = (const float*)d_in[0];
  const float* rw  = (const float*)d_in[1];
  const float* rb  = (const float*)d_in[2];
  const float* wgu = (const float*)d_in[3];
  const float* gub = (const float*)d_in[4];
  const float* wdn = (const float*)d_in[5];
  const float* dnb = (const float*)d_in[6];
  float* out = (float*)d_out;
  float* scores = out + (size_t)Sd * Hd;

  char* ws = (char*)d_ws;
  int* cnt     = (int*)ws;                            // 32 B
  int* assign  = (int*)(ws + 256);                    // 64 KiB
  float* topw  = (float*)(ws + 256 + 65536);          // 16 KiB
  __bf16* xb   = (__bf16*)(ws + (1 << 20));           // 4 MiB
  __bf16* abuf = (__bf16*)(ws + ((size_t)6 << 20));   // <=12.6 MiB
  __bf16* w1f  = (__bf16*)(ws + ((size_t)19 << 20));  // 32 MiB
  __bf16* w2f  = (__bf16*)(ws + ((size_t)19 << 20));  // aliases w1f (16 MiB)

  hipMemsetAsync(out, 0, (size_t)Sd * Hd * sizeof(float), stream);
  hipMemsetAsync(cnt, 0, 32, stream);

  k_router<<<512, 256, 0, stream>>>(x, rw, rb, scores, topw, cnt, assign);
  k_prex<<<1024, 256, 0, stream>>>(x, xb);
  k_pre1<<<1024, 256, 0, stream>>>(wgu, w1f);
  k_gemm1<<<512, 256, 0, stream>>>(xb, w1f, gub, cnt, assign, abuf);
  k_pre2<<<512, 256, 0, stream>>>(wdn, w2f);  // w2f overwrites w1f (dead now)
  k_gemm2<<<512, 256, 0, stream>>>(abuf, w2f, dnb, cnt, assign, topw, out);
}

// Round 6
// 197.741 us; speedup vs baseline: 1.0977x; 1.0977x over previous
//
#include <hip/hip_runtime.h>
#include <stdint.h>

// A2aSparseMLP: B=1, S=2048, H=1024, I=1024, E=8, TOP_K=2, ALPHA=1.702, LIMIT=7
// Round 6: latency attack. 512-thread GEMM blocks (4 waves/SIMD), depth-4
// static A-prefetch ring, barrier trim, prex fused into router.
// Streaming-transpose pre-passes and panel-resident GEMM structure from R5.

#define Sd 2048
#define Hd 1024
#define Id 1024

typedef __bf16 bf16x8 __attribute__((ext_vector_type(8)));
typedef float f32x4 __attribute__((ext_vector_type(4)));

__device__ __forceinline__ f32x4 mfma_bf16(bf16x8 a, bf16x8 b, f32x4 c) {
  return __builtin_amdgcn_mfma_f32_16x16x32_bf16(a, b, c, 0, 0, 0);
}

__device__ __forceinline__ void gload16(const __bf16* g, __bf16* l) {
  __builtin_amdgcn_global_load_lds(
      (const __attribute__((address_space(1))) unsigned int*)g,
      (__attribute__((address_space(3))) unsigned int*)l, 16, 0, 0);
}

__device__ __forceinline__ unsigned int packbf(float lo, float hi) {
  __bf16 a = (__bf16)lo, b = (__bf16)hi;
  return (unsigned int)__builtin_bit_cast(unsigned short, a) |
         ((unsigned int)__builtin_bit_cast(unsigned short, b) << 16);
}

// ---------------- router (+ x -> bf16 xb) ----------------
__global__ __launch_bounds__(256) void k_router(
    const float* __restrict__ x, const float* __restrict__ rw,
    const float* __restrict__ rb, float* __restrict__ scores,
    float* __restrict__ topw, int* __restrict__ cnt, int* __restrict__ assign,
    __bf16* __restrict__ xb) {
  const int lane = threadIdx.x & 63;
  const int t = blockIdx.x * 4 + (threadIdx.x >> 6);
  float acc[8];
#pragma unroll
  for (int e = 0; e < 8; ++e) acc[e] = 0.f;
  const float* xr = x + (size_t)t * Hd;
#pragma unroll
  for (int j = 0; j < 16; ++j) {
    int h = j * 64 + lane;
    float xv = xr[h];
    xb[(size_t)t * Hd + h] = (__bf16)xv;
    const float4* wp = (const float4*)(rw + h * 8);
    float4 w0 = wp[0], w1 = wp[1];
    acc[0] += xv * w0.x; acc[1] += xv * w0.y;
    acc[2] += xv * w0.z; acc[3] += xv * w0.w;
    acc[4] += xv * w1.x; acc[5] += xv * w1.y;
    acc[6] += xv * w1.z; acc[7] += xv * w1.w;
  }
#pragma unroll
  for (int m = 32; m >= 1; m >>= 1) {
#pragma unroll
    for (int e = 0; e < 8; ++e) acc[e] += __shfl_xor(acc[e], m, 64);
  }
  if (lane == 0) {
    float lg[8];
#pragma unroll
    for (int e = 0; e < 8; ++e) lg[e] = acc[e] + rb[e];
    int i0 = 0; float v0 = lg[0];
#pragma unroll
    for (int e = 1; e < 8; ++e) if (lg[e] > v0) { v0 = lg[e]; i0 = e; }
    int i1 = -1; float v1 = -3.4e38f;
#pragma unroll
    for (int e = 0; e < 8; ++e) if (e != i0 && lg[e] > v1) { v1 = lg[e]; i1 = e; }
    float e1 = __expf(v1 - v0);
    float s = 1.f + e1;
    float w0 = 1.f / s, w1v = e1 / s;
#pragma unroll
    for (int e = 0; e < 8; ++e)
      scores[t * 8 + e] = (e == i0) ? w0 : ((e == i1) ? w1v : 0.f);
    topw[t * 2] = w0;
    topw[t * 2 + 1] = w1v;
    int s0 = atomicAdd(&cnt[i0], 1); assign[i0 * 2048 + s0] = t * 2;
    int s1 = atomicAdd(&cnt[i1], 1); assign[i1 * 2048 + s1] = t * 2 + 1;
  }
}

// ------ pre1: wgu f32 (row-major, g/u interleaved) -> w1f bf16 frag order ------
__global__ __launch_bounds__(256) void k_pre1(const float* __restrict__ wgu,
                                              __bf16* __restrict__ w1f) {
  const int b = blockIdx.x;
  const int nt = b & 7, kt = (b >> 3) & 15, e = b >> 7;
  __shared__ unsigned int Ls[16][16][34];  // [vu][c][r]
  const int tid = threadIdx.x;
  const int w = tid >> 6, lane = tid & 63;
  const float* src = wgu + (size_t)e * (1024 * 2048) +
                     (size_t)(kt * 64 + w * 16) * 2048 + nt * 256;
  const int i0 = lane * 2;
  const int c0 = i0 & 15, u0 = (i0 >> 4) * 2;
  const int c1 = (i0 + 1) & 15, u1 = ((i0 + 1) >> 4) * 2;
#pragma unroll
  for (int rp = 0; rp < 8; ++rp) {
    float4 fa = *(const float4*)(src + (size_t)(rp * 2) * 2048 + lane * 4);
    float4 fb = *(const float4*)(src + (size_t)(rp * 2 + 1) * 2048 + lane * 4);
    int r = w * 8 + rp;
    Ls[u0][c0][r] = packbf(fa.x, fb.x);
    Ls[u0 + 1][c0][r] = packbf(fa.y, fb.y);
    Ls[u1][c1][r] = packbf(fa.z, fb.z);
    Ls[u1 + 1][c1][r] = packbf(fa.w, fb.w);
  }
  __syncthreads();
  const int khi = lane >> 4, c = lane & 15;
#pragma unroll
  for (int uu = 0; uu < 8; ++uu) {
    int ul = w * 8 + uu, vu = ul >> 1, k32l = ul & 1;
    const unsigned int* p = &Ls[vu][c][k32l * 16 + khi * 4];
    uint2 q0 = *(const uint2*)p;
    uint2 q1 = *(const uint2*)(p + 2);
    int itg = nt * 8 + (vu >> 1), vf = vu & 1;
    size_t row = ((size_t)(e * 64 + itg) * 2 + vf) * 32 + (kt * 2 + k32l);
    uint4 o = {q0.x, q0.y, q1.x, q1.y};
    *(uint4*)(w1f + row * 512 + lane * 8) = o;
  }
}

// ------ pre2: wdn f32 -> w2f bf16 frag order (streaming transpose) ------
__global__ __launch_bounds__(256) void k_pre2(const float* __restrict__ wdn,
                                              __bf16* __restrict__ w2f) {
  const int b = blockIdx.x;
  const int nt = b & 3, kt = (b >> 2) & 15, e = b >> 6;
  __shared__ unsigned int Ls[16][16][34];
  const int tid = threadIdx.x;
  const int w = tid >> 6, lane = tid & 63;
  const float* src = wdn + (size_t)e * (1024 * 1024) +
                     (size_t)(kt * 64 + w * 16) * 1024 + nt * 256;
#pragma unroll
  for (int rp = 0; rp < 8; ++rp) {
    float4 fa = *(const float4*)(src + (size_t)(rp * 2) * 1024 + lane * 4);
    float4 fb = *(const float4*)(src + (size_t)(rp * 2 + 1) * 1024 + lane * 4);
    int r = w * 8 + rp;
    float va[4] = {fa.x, fa.y, fa.z, fa.w};
    float vb[4] = {fb.x, fb.y, fb.z, fb.w};
#pragma unroll
    for (int q = 0; q < 4; ++q) {
      int cl = lane * 4 + q;
      Ls[cl >> 4][cl & 15][r] = packbf(va[q], vb[q]);
    }
  }
  __syncthreads();
  const int khi = lane >> 4, c = lane & 15;
#pragma unroll
  for (int uu = 0; uu < 8; ++uu) {
    int ul = w * 8 + uu, Fl = ul >> 1, k32l = ul & 1;
    const unsigned int* p = &Ls[Fl][c][k32l * 16 + khi * 4];
    uint2 q0 = *(const uint2*)p;
    uint2 q1 = *(const uint2*)(p + 2);
    size_t row = (size_t)(e * 64 + nt * 16 + Fl) * 32 + (kt * 2 + k32l);
    uint4 o = {q0.x, q0.y, q1.x, q1.y};
    *(uint4*)(w2f + row * 512 + lane * 8) = o;
  }
}

// ------ GEMM1: B-resident (e, it: 16 act cols), 8 waves, D=4 A-prefetch ------
__global__ __launch_bounds__(512, 4) void k_gemm1(
    const __bf16* __restrict__ xb, const __bf16* __restrict__ w1f,
    const float* __restrict__ gub, const int* __restrict__ cnt,
    const int* __restrict__ assign, __bf16* __restrict__ abuf) {
  const int it = blockIdx.x & 63;
  const int e = blockIdx.x >> 6;
  const int n = cnt[e];
  if (n <= 0) return;
  __shared__ __align__(16) __bf16 Bs[2][32][512];
  __shared__ __align__(16) __bf16 Ts[256][16];
  __shared__ int ent[256];
  const int tid = threadIdx.x;
  const int lane = tid & 63;
  const int wv = tid >> 6;  // 0..7, wave = 32-row band

  // stage B panel once: contiguous 64 KB via global_load_lds
  const __bf16* wbase = w1f + (size_t)((e * 64 + it) * 2) * (32 * 512);
  __bf16* bsf = &Bs[0][0][0];
#pragma unroll
  for (int s = 0; s < 8; ++s) {
    int idx = s * 512 + tid;
    gload16(wbase + (size_t)idx * 8, bsf + (size_t)idx * 8);
  }
  const int iCol = it * 16 + (lane & 15);
  const float bg = gub[e * 2048 + 2 * iCol];
  const float bu = gub[e * 2048 + 2 * iCol + 1];
  int eb = 0;
#pragma unroll
  for (int q = 0; q < 8; ++q) eb += (q < e) ? (((cnt[q] + 255) >> 8) << 8) : 0;
  const int u0 = eb >> 4;
  const int nmt = (n + 255) >> 8;

  for (int mt = 0; mt < nmt; ++mt) {
    if (tid < 256) {
      int slot = mt * 256 + tid;
      ent[tid] = (slot < n) ? assign[e * 2048 + slot] : -1;
    }
    __syncthreads();  // publish ent; first iter also drains panel gloads;
                      // also orders prev iter's Ts reads before epilogue writes
    const __bf16* ap[2];
#pragma unroll
    for (int mi = 0; mi < 2; ++mi) {
      int en = ent[wv * 32 + mi * 16 + (lane & 15)];
      int tok = (en >= 0) ? (en >> 1) : 0;
      ap[mi] = xb + (size_t)tok * Hd + ((lane >> 4) * 8);
    }
    f32x4 acc[2][2];
#pragma unroll
    for (int a = 0; a < 2; ++a)
#pragma unroll
      for (int b = 0; b < 2; ++b) acc[a][b] = (f32x4){0.f, 0.f, 0.f, 0.f};
    bf16x8 pf[4][2];
#pragma unroll
    for (int d = 0; d < 4; ++d) {
      pf[d][0] = *(const bf16x8*)(ap[0] + d * 32);
      pf[d][1] = *(const bf16x8*)(ap[1] + d * 32);
    }
#pragma unroll 4
    for (int ks = 0; ks < 28; ++ks) {
      bf16x8 b0 = *(const bf16x8*)&Bs[0][ks][lane * 8];
      bf16x8 b1 = *(const bf16x8*)&Bs[1][ks][lane * 8];
      acc[0][0] = mfma_bf16(pf[ks & 3][0], b0, acc[0][0]);
      acc[0][1] = mfma_bf16(pf[ks & 3][0], b1, acc[0][1]);
      acc[1][0] = mfma_bf16(pf[ks & 3][1], b0, acc[1][0]);
      acc[1][1] = mfma_bf16(pf[ks & 3][1], b1, acc[1][1]);
      pf[ks & 3][0] = *(const bf16x8*)(ap[0] + (ks + 4) * 32);
      pf[ks & 3][1] = *(const bf16x8*)(ap[1] + (ks + 4) * 32);
    }
#pragma unroll
    for (int ks = 28; ks < 32; ++ks) {
      bf16x8 b0 = *(const bf16x8*)&Bs[0][ks][lane * 8];
      bf16x8 b1 = *(const bf16x8*)&Bs[1][ks][lane * 8];
      acc[0][0] = mfma_bf16(pf[ks & 3][0], b0, acc[0][0]);
      acc[0][1] = mfma_bf16(pf[ks & 3][0], b1, acc[0][1]);
      acc[1][0] = mfma_bf16(pf[ks & 3][1], b0, acc[1][0]);
      acc[1][1] = mfma_bf16(pf[ks & 3][1], b1, acc[1][1]);
    }
    // epilogue: GLU -> Ts
#pragma unroll
    for (int mi = 0; mi < 2; ++mi) {
#pragma unroll
      for (int rr = 0; rr < 4; ++rr) {
        int row = wv * 32 + mi * 16 + (lane >> 4) * 4 + rr;
        float g = fminf(acc[mi][0][rr] + bg, 7.f);
        float u = fminf(fmaxf(acc[mi][1][rr] + bu, -7.f), 7.f);
        float sg = 1.f / (1.f + __expf(-1.702f * g));
        Ts[row][lane & 15] = (__bf16)((u + 1.f) * (g * sg));
      }
    }
    __syncthreads();  // Ts ready
    {
      int r = tid & 15, hl = (tid >> 4) & 1, sbl = tid >> 5;
      bf16x8 v = *(const bf16x8*)&Ts[sbl * 16 + r][hl * 8];
      size_t o = (((size_t)(u0 + mt * 16 + sbl) * 32) + (it >> 1)) * 512 +
                 ((((it & 1) * 2 + hl) * 16 + r) * 8);
      *(bf16x8*)(abuf + o) = v;
    }
  }
}

// ------ GEMM2: B-resident (e, ht: 32 h cols, ms), 8 waves, D=4 prefetch ------
__global__ __launch_bounds__(512, 4) void k_gemm2(
    const __bf16* __restrict__ abuf, const __bf16* __restrict__ w2f,
    const float* __restrict__ dnb, const int* __restrict__ cnt,
    const int* __restrict__ assign, const float* __restrict__ topw,
    float* __restrict__ out) {
  const int ms = blockIdx.x & 1;
  const int ht = (blockIdx.x >> 1) & 31;
  const int e = blockIdx.x >> 6;
  const int n = cnt[e];
  if (n <= 0) return;
  __shared__ __align__(16) __bf16 Bs[2][32][512];
  __shared__ int ent[256];
  __shared__ float wgt[256];
  const int tid = threadIdx.x;
  const int lane = tid & 63;
  const int wv = tid >> 6;

  const __bf16* wbase = w2f + (size_t)(e * 64 + ht * 2) * (32 * 512);
  __bf16* bsf = &Bs[0][0][0];
#pragma unroll
  for (int s = 0; s < 8; ++s) {
    int idx = s * 512 + tid;
    gload16(wbase + (size_t)idx * 8, bsf + (size_t)idx * 8);
  }
  int eb = 0;
#pragma unroll
  for (int q = 0; q < 8; ++q) eb += (q < e) ? (((cnt[q] + 255) >> 8) << 8) : 0;
  const int u0 = eb >> 4;
  const int nmt = (n + 255) >> 8;

  for (int mt = ms; mt < nmt; mt += 2) {
    __syncthreads();  // prev epilogue's ent/wgt reads done
    if (tid < 256) {
      int slot = mt * 256 + tid;
      int en = (slot < n) ? assign[e * 2048 + slot] : -1;
      ent[tid] = en;
      wgt[tid] = (en >= 0) ? topw[en] : 0.f;
    }
    __syncthreads();  // publish (first iter also drains panel gloads)
    const __bf16* ab[2];
#pragma unroll
    for (int mi = 0; mi < 2; ++mi)
      ab[mi] = abuf + ((size_t)(u0 + mt * 16 + wv * 2 + mi) * 32) * 512 + lane * 8;
    f32x4 acc[2][2];
#pragma unroll
    for (int a = 0; a < 2; ++a)
#pragma unroll
      for (int b = 0; b < 2; ++b) acc[a][b] = (f32x4){0.f, 0.f, 0.f, 0.f};
    bf16x8 pf[4][2];
#pragma unroll
    for (int d = 0; d < 4; ++d) {
      pf[d][0] = *(const bf16x8*)(ab[0] + d * 512);
      pf[d][1] = *(const bf16x8*)(ab[1] + d * 512);
    }
#pragma unroll 4
    for (int ks = 0; ks < 28; ++ks) {
      bf16x8 b0 = *(const bf16x8*)&Bs[0][ks][lane * 8];
      bf16x8 b1 = *(const bf16x8*)&Bs[1][ks][lane * 8];
      acc[0][0] = mfma_bf16(pf[ks & 3][0], b0, acc[0][0]);
      acc[0][1] = mfma_bf16(pf[ks & 3][0], b1, acc[0][1]);
      acc[1][0] = mfma_bf16(pf[ks & 3][1], b0, acc[1][0]);
      acc[1][1] = mfma_bf16(pf[ks & 3][1], b1, acc[1][1]);
      pf[ks & 3][0] = *(const bf16x8*)(ab[0] + (ks + 4) * 512);
      pf[ks & 3][1] = *(const bf16x8*)(ab[1] + (ks + 4) * 512);
    }
#pragma unroll
    for (int ks = 28; ks < 32; ++ks) {
      bf16x8 b0 = *(const bf16x8*)&Bs[0][ks][lane * 8];
      bf16x8 b1 = *(const bf16x8*)&Bs[1][ks][lane * 8];
      acc[0][0] = mfma_bf16(pf[ks & 3][0], b0, acc[0][0]);
      acc[0][1] = mfma_bf16(pf[ks & 3][0], b1, acc[0][1]);
      acc[1][0] = mfma_bf16(pf[ks & 3][1], b0, acc[1][0]);
      acc[1][1] = mfma_bf16(pf[ks & 3][1], b1, acc[1][1]);
    }
#pragma unroll
    for (int ni = 0; ni < 2; ++ni) {
      const int nn = ht * 32 + ni * 16 + (lane & 15);
      const float bias = dnb[e * 1024 + nn];
#pragma unroll
      for (int mi = 0; mi < 2; ++mi) {
#pragma unroll
        for (int rr = 0; rr < 4; ++rr) {
          int row = wv * 32 + mi * 16 + (lane >> 4) * 4 + rr;
          int en = ent[row];
          if (en >= 0)
            atomicAdd(out + (size_t)(en >> 1) * Hd + nn,
                      wgt[row] * (acc[mi][ni][rr] + bias));
        }
      }
    }
  }
}

extern "C" void kernel_launch(void* const* d_in, const int* in_sizes, int n_in,
                              void* d_out, int out_size, void* d_ws, size_t ws_size,
                              hipStream_t stream) {
  const float* x   = (const float*)d_in[0];
  const float* rw  = (const float*)d_in[1];
  const float* rb  = (const float*)d_in[2];
  const float* wgu = (const float*)d_in[3];
  const float* gub = (const float*)d_in[4];
  const float* wdn = (const float*)d_in[5];
  const float* dnb = (const float*)d_in[6];
  float* out = (float*)d_out;
  float* scores = out + (size_t)Sd * Hd;

  char* ws = (char*)d_ws;
  int* cnt     = (int*)ws;                            // 32 B
  int* assign  = (int*)(ws + 256);                    // 64 KiB
  float* topw  = (float*)(ws + 256 + 65536);          // 16 KiB
  __bf16* xb   = (__bf16*)(ws + (1 << 20));           // 4 MiB
  __bf16* abuf = (__bf16*)(ws + ((size_t)6 << 20));   // <=12.6 MiB
  __bf16* w1f  = (__bf16*)(ws + ((size_t)19 << 20));  // 32 MiB
  __bf16* w2f  = (__bf16*)(ws + ((size_t)19 << 20));  // aliases w1f (16 MiB)

  hipMemsetAsync(out, 0, (size_t)Sd * Hd * sizeof(float), stream);
  hipMemsetAsync(cnt, 0, 32, stream);

  k_router<<<512, 256, 0, stream>>>(x, rw, rb, scores, topw, cnt, assign, xb);
  k_pre1<<<1024, 256, 0, stream>>>(wgu, w1f);
  k_gemm1<<<512, 512, 0, stream>>>(xb, w1f, gub, cnt, assign, abuf);
  k_pre2<<<512, 256, 0, stream>>>(wdn, w2f);  // w2f overwrites w1f (dead now)
  k_gemm2<<<512, 512, 0, stream>>>(abuf, w2f, dnb, cnt, assign, topw, out);
}